// Round 3
// baseline (949.691 us; speedup 1.0000x reference)
//
#include <hip/hip_runtime.h>
#include <math.h>

// out[b] = (1^T · Π_d C_d · P) · Π_d x[b,d] + bias — per-row scalars commute
// out of the batch-independent matrix chain.
//
// ROUND 10 (this round): single kernel. Round-9 measured ~23 us of kernel
// region = fused (~15) + launch gap (~5) + mps_scale (~2). Kill the second
// launch: row blocks scale + write out THEMSELVES after an acquire-spin on
// a pE-ready flag. Spin is safe (no thrash, unlike prior rounds 7/8):
//   - chain blocks are blockIdx 0..31 -> dispatched first, never wait on
//     row blocks -> no deadlock;
//   - a row block spins only AFTER its full 8 KiB/row stream (work done);
//     pE lands ~13 us, stream takes ~11 us -> waits are short;
//   - s_sleep(16) backoff keeps flag-line L2 traffic ~1 poll/0.4us/wave.
// Chain path verbatim round-9 (26 KB LDS, 6 blocks/CU, reg-prefetched core
// ping-pong, flag fan-in, block-0 staged register fold + projection).
// Row products underflow fp32 to 0 exactly as the reference (absmax 0.0).

#define DFEAT 2048
#define R 16
#define NR2 256               // R*R
#define OUTD 64
#define CHUNK 64              // cores folded per chain block
#define NCHUNK (DFEAT / CHUNK)    // 32 chain blocks
#define MAGIC 0x7E57C0DE

// (Arow · B)[c0..c0+3]: Arow = 16 LDS floats (4x ds_read_b128), B = 16x16
// row-major LDS matrix. All FMA, no barriers. (verbatim)
__device__ __forceinline__ float4 rowmul(const float* Arow, const float* B,
                                         int c0) {
    float4 acc = {0.f, 0.f, 0.f, 0.f};
    const float4* a4 = (const float4*)Arow;
#pragma unroll
    for (int kk = 0; kk < 4; ++kk) {
        const float4 av = a4[kk];
        const float4 b0 = *(const float4*)&B[(4 * kk + 0) * 16 + c0];
        const float4 b1 = *(const float4*)&B[(4 * kk + 1) * 16 + c0];
        const float4 b2 = *(const float4*)&B[(4 * kk + 2) * 16 + c0];
        const float4 b3 = *(const float4*)&B[(4 * kk + 3) * 16 + c0];
        acc.x = fmaf(av.x, b0.x, fmaf(av.y, b1.x, fmaf(av.z, b2.x, fmaf(av.w, b3.x, acc.x))));
        acc.y = fmaf(av.x, b0.y, fmaf(av.y, b1.y, fmaf(av.z, b2.y, fmaf(av.w, b3.y, acc.y))));
        acc.z = fmaf(av.x, b0.z, fmaf(av.y, b1.z, fmaf(av.z, b2.z, fmaf(av.w, b3.z, acc.z))));
        acc.w = fmaf(av.x, b0.w, fmaf(av.y, b1.w, fmaf(av.z, b2.w, fmaf(av.w, b3.w, acc.w))));
    }
    return acc;
}

__global__ __launch_bounds__(256) void mps_fused(const float* __restrict__ cores,
                                                 const float* __restrict__ proj,
                                                 const float* __restrict__ x,
                                                 const float* __restrict__ bias,
                                                 float* __restrict__ out,
                                                 float* __restrict__ partials,
                                                 int* __restrict__ flags,
                                                 float* __restrict__ pE,
                                                 int B) {
    // 26 KB total -> 6 blocks/CU (156 KB), 24 waves/CU for the row stream.
    __shared__ __align__(16) float Bb[4][2][NR2];   // 8 KB per-wave core pp
    __shared__ __align__(16) float Aw[4][2][NR2];   // 8 KB per-wave A pp
    __shared__ __align__(16) float F[2][NR2];       // 2 KB combine pp
    __shared__ __align__(16) float Pt[8 * NR2];     // 8 KB partial stage

    const int tid  = threadIdx.x;
    const int wave = tid >> 6, lane = tid & 63;

    if (blockIdx.x >= NCHUNK) {
        // ============ row block: stream product, then scale + write ========
        const int row = (blockIdx.x - NCHUNK) * 4 + wave;
        if (row >= B) return;
        const float4* xr = (const float4*)(x + (size_t)row * DFEAT);
        float prod = 1.f;
#pragma unroll
        for (int it = 0; it < DFEAT / (64 * 4); ++it) {   // 8 iters, 1 KiB/instr
            float4 v = xr[it * 64 + lane];
            prod *= (v.x * v.y) * (v.z * v.w);
        }
#pragma unroll
        for (int off = 32; off > 0; off >>= 1)            // wave-wide product
            prod *= __shfl_xor(prod, off);

        // pE-ready spin: work is already done; chain (blocks 0..31) was
        // dispatched first and never waits on us -> guaranteed progress.
        while (__hip_atomic_load(&flags[0], __ATOMIC_ACQUIRE,
                                 __HIP_MEMORY_SCOPE_AGENT) != MAGIC)
            __builtin_amdgcn_s_sleep(16);                 // ~1k cycles backoff

        const float pv = pE[lane];                        // lane < 64 == OUTD
        const int   E  = ((const int*)pE)[OUTD];
        out[(size_t)row * OUTD + lane] = ldexpf(pv * prod, E) + bias[lane];
        return;
    }

    // ==================== chain block (blockIdx.x < 32) =====================
    const int ri = lane >> 2;             // row 0..15 (this lane's A/F row)
    const int c0 = (lane & 3) << 2;       // col base 0,4,8,12
    const size_t d0 = (size_t)blockIdx.x * CHUNK;

    // ---- per-wave fold of 16 matrices, wave-synchronous (no barriers) ----
    // Cores reg-prefetched one ahead, double-buffered in 1 KB LDS ping-pong.
    const float* gw = cores + (d0 + 16 * wave) * NR2;
    *(float4*)&Aw[wave][0][lane * 4] = *(const float4*)&gw[lane * 4];  // A=core0
    float4 nxt = *(const float4*)&gw[NR2 + lane * 4];                  // core1
    int cur = 0;
    for (int t = 1; t < 16; ++t) {        // 15 multiplies -> result in buf 1
        *(float4*)&Bb[wave][t & 1][lane * 4] = nxt;    // stash core t
        if (t < 15)                                    // prefetch core t+1
            nxt = *(const float4*)&gw[(size_t)(t + 1) * NR2 + lane * 4];
        float4 r = rowmul(&Aw[wave][cur][ri * 16], &Bb[wave][t & 1][0], c0);
        *(float4*)&Aw[wave][cur ^ 1][ri * 16 + c0] = r;
        cur ^= 1;
    }
    __syncthreads();                      // all 4 wave-products ready

    // ---- wave 0 combines: F = Aw0 x Aw1 x Aw2 x Aw3 (3 multiplies) ----
    if (wave == 0) {
        *(float4*)&F[0][ri * 16 + c0] =
            *(const float4*)&Aw[0][1][ri * 16 + c0];
        int cc = 0;
        for (int w = 1; w < 4; ++w) {     // 3 multiplies -> result in F[1]
            float4 r = rowmul(&F[cc][ri * 16], &Aw[w][1][0], c0);
            *(float4*)&F[cc ^ 1][ri * 16 + c0] = r;
            cc ^= 1;
        }
    }
    __syncthreads();
    const int i = tid >> 4, j = tid & 15;
    const float v = F[1][tid];            // element (i,j) of chunk product

    if (blockIdx.x != 0) {
        // ---- producer: publish partial, release flag (verbatim) ----
        partials[blockIdx.x * NR2 + tid] = v;
        __syncthreads();                  // block stores complete at L2
        if (tid == 0)
            __hip_atomic_store(&flags[blockIdx.x], MAGIC,
                               __ATOMIC_RELEASE, __HIP_MEMORY_SCOPE_AGENT);
        return;
    }

    // ---- block 0: own partial straight into LDS slot 0 (transposed) ----
    Pt[0 * 256 + j * 16 + i] = v;

    // acquire-spin for producers 1..31 (every thread: cache-inv side effect)
    {
        const int f = 1 + (tid % (NCHUNK - 1));
        while (__hip_atomic_load(&flags[f], __ATOMIC_ACQUIRE,
                                 __HIP_MEMORY_SCOPE_AGENT) != MAGIC) { }
    }
    __syncthreads();

    // ---- 4 rounds: stage 8 partials transposed (8 KB) + wave-0 fold ----
    float w = 1.f;                        // fold state lives in wave-0 regs
    int E = 0;
    for (int rr = 0; rr < 4; ++rr) {
#pragma unroll
        for (int q = 0; q < 2; ++q) {                 // 512 float4 / round
            const int idx = q * 256 + tid;
            const int flat = idx * 4;
            const int s = flat >> 8;                  // local slot 0..7
            if (rr > 0 || s > 0) {                    // slot 0 of rr=0 = own
                float4 p4 =
                    ((const float4*)(partials + (size_t)(8 * rr) * NR2))[idx];
                const int e = flat & 255;
                const int k = e >> 4, j0 = e & 15;    // row k, cols j0..j0+3
                Pt[s * 256 + (j0 + 0) * 16 + k] = p4.x;
                Pt[s * 256 + (j0 + 1) * 16 + k] = p4.y;
                Pt[s * 256 + (j0 + 2) * 16 + k] = p4.z;
                Pt[s * 256 + (j0 + 3) * 16 + k] = p4.w;
            }
        }
        __syncthreads();
        if (tid < 64) {                   // wave-0 register fold, 8 per round
            const int jj = tid & 15, q = tid >> 4;    // lane = jj + 16*q
            for (int s = 0; s < 8; ++s) {
                const float4 pr = *(const float4*)&Pt[s * 256 + jj * 16 + 4 * q];
                float sum;
                sum = __shfl(w, 4 * q + 0) * pr.x;    // w[k] lives at lane k
                sum = fmaf(__shfl(w, 4 * q + 1), pr.y, sum);
                sum = fmaf(__shfl(w, 4 * q + 2), pr.z, sum);
                sum = fmaf(__shfl(w, 4 * q + 3), pr.w, sum);
                sum += __shfl_xor(sum, 16);           // sum the 4 q-groups
                sum += __shfl_xor(sum, 32);           // -> nw[jj], replicated
                w = sum;
            }
            // renorm once per round (global gg = 8*rr+7 -> gg&7==7, as before)
            float m = fabsf(w);
#pragma unroll
            for (int off = 1; off <= 8; off <<= 1)
                m = fmaxf(m, __shfl_xor(m, off));
            if (m > 0.f) {
                int e2 = 0;
                (void)frexpf(m, &e2);                 // m = f*2^e, f in [.5,1)
                w = ldexpf(w, -e2);                   // exact rescale
                E += e2;
            }
        }
        __syncthreads();                  // Pt reusable next round
    }

    if (tid < 64) {
        // p[o] = sum_k w[k] * proj[k][o]
        float p = 0.f;
#pragma unroll
        for (int k = 0; k < R; ++k)
            p = fmaf(__shfl(w, k), proj[k * OUTD + tid], p);
        pE[tid] = p;
        if (tid == 0) ((int*)pE)[OUTD] = E;
    }
    __syncthreads();                      // pE stores drained (vmcnt) + visible
    if (tid == 0)
        __hip_atomic_store(&flags[0], MAGIC,
                           __ATOMIC_RELEASE, __HIP_MEMORY_SCOPE_AGENT);
}

// ---------------------------------------------------------------------------
extern "C" void kernel_launch(void* const* d_in, const int* in_sizes, int n_in,
                              void* d_out, int out_size, void* d_ws, size_t ws_size,
                              hipStream_t stream) {
    const float* inputs = (const float*)d_in[0];   // (B, 2048) fp32
    const float* cores  = (const float*)d_in[1];   // (2048, 16, 16) fp32
    const float* proj   = (const float*)d_in[2];   // (16, 64) fp32
    const float* bias   = (const float*)d_in[3];   // (64,) fp32
    float* out = (float*)d_out;                    // (B, 64) fp32

    const int B = in_sizes[0] / DFEAT;             // 8192

    // ws layout (16B aligned): partials | pE (64f + int E, pad) | flags
    float* partials = (float*)d_ws;                // 32*256 floats (32 KiB)
    float* pE    = partials + NCHUNK * NR2;        // 64 floats + int E (+pad)
    int*   flags = (int*)(pE + 68);                // 32 ints; harness poison
                                                   // != MAGIC each replay

    const int rowBlocks = (B + 3) / 4;             // 4 rows (waves) per block
    mps_fused<<<NCHUNK + rowBlocks, 256, 0, stream>>>(cores, proj, inputs,
                                                      bias, out, partials,
                                                      flags, pE, B);
}

// Round 4
// 104.840 us; speedup vs baseline: 9.0585x; 9.0585x over previous
//
#include <hip/hip_runtime.h>
#include <math.h>

// out[b] = (1^T · Π_d C_d · P) · Π_d x[b,d] + bias — per-row scalars commute
// out of the batch-independent matrix chain.
//
// ROUND 11: revert to the VERIFIED round-2 two-kernel structure (105.2 us).
// Round-3's grid-scale consumer spin (8192 waves polling flags[0] with
// agent-scope acquire) caused a coherence-invalidation storm: 934 us,
// VALUBusy 0.16%. Rule: few spinners only (the 31-producer fan-in is fine).
//
// THIS ROUND's change, inside the chain path only: round-9's depth-1 core
// prefetch made the per-wave fold a serial latency chain (15 dependent
// ~1 KiB loads ≈ 5-9 us). Now ALL 16 cores are loaded into registers up
// front (float4 pre[16], fully unrolled -> static indices, full memory
// parallelism restored, one latency exposure). LDS stays 26 KB ->
// 6 blocks/CU; VGPR ~100 still far under the 6-waves/SIMD budget.
//   mps_fused (32 chain + 2048 row blocks): chain folds 64-core chunks
//     (wave-parallel tree fold, flag fan-in, block-0 register fold ->
//     pE); row blocks stream the compulsory 64 MB, write prod, EXIT.
//   mps_scale (2048 blocks): out = ldexp(pE[o]*prod[b],E)+bias, 2 MB.
// Row products underflow fp32 to 0 exactly as the reference (absmax 0.0).

#define DFEAT 2048
#define R 16
#define NR2 256               // R*R
#define OUTD 64
#define CHUNK 64              // cores folded per chain block
#define NCHUNK (DFEAT / CHUNK)    // 32 chain blocks
#define MAGIC 0x7E57C0DE

// (Arow · B)[c0..c0+3]: Arow = 16 LDS floats (4x ds_read_b128), B = 16x16
// row-major LDS matrix. All FMA, no barriers. (verbatim)
__device__ __forceinline__ float4 rowmul(const float* Arow, const float* B,
                                         int c0) {
    float4 acc = {0.f, 0.f, 0.f, 0.f};
    const float4* a4 = (const float4*)Arow;
#pragma unroll
    for (int kk = 0; kk < 4; ++kk) {
        const float4 av = a4[kk];
        const float4 b0 = *(const float4*)&B[(4 * kk + 0) * 16 + c0];
        const float4 b1 = *(const float4*)&B[(4 * kk + 1) * 16 + c0];
        const float4 b2 = *(const float4*)&B[(4 * kk + 2) * 16 + c0];
        const float4 b3 = *(const float4*)&B[(4 * kk + 3) * 16 + c0];
        acc.x = fmaf(av.x, b0.x, fmaf(av.y, b1.x, fmaf(av.z, b2.x, fmaf(av.w, b3.x, acc.x))));
        acc.y = fmaf(av.x, b0.y, fmaf(av.y, b1.y, fmaf(av.z, b2.y, fmaf(av.w, b3.y, acc.y))));
        acc.z = fmaf(av.x, b0.z, fmaf(av.y, b1.z, fmaf(av.z, b2.z, fmaf(av.w, b3.z, acc.z))));
        acc.w = fmaf(av.x, b0.w, fmaf(av.y, b1.w, fmaf(av.z, b2.w, fmaf(av.w, b3.w, acc.w))));
    }
    return acc;
}

__global__ __launch_bounds__(256) void mps_fused(const float* __restrict__ cores,
                                                 const float* __restrict__ proj,
                                                 const float* __restrict__ x,
                                                 float* __restrict__ prodbuf,
                                                 float* __restrict__ partials,
                                                 int* __restrict__ flags,
                                                 float* __restrict__ pE,
                                                 int B) {
    // 26 KB total -> 6 blocks/CU (156 KB), 24 waves/CU for the row stream.
    __shared__ __align__(16) float Bb[4][2][NR2];   // 8 KB per-wave core pp
    __shared__ __align__(16) float Aw[4][2][NR2];   // 8 KB per-wave A pp
    __shared__ __align__(16) float F[2][NR2];       // 2 KB combine pp
    __shared__ __align__(16) float Pt[8 * NR2];     // 8 KB partial stage

    const int tid  = threadIdx.x;
    const int wave = tid >> 6, lane = tid & 63;

    if (blockIdx.x >= NCHUNK) {
        // ================= row block: streaming product, no waits ==========
        const int row = (blockIdx.x - NCHUNK) * 4 + wave;
        if (row >= B) return;
        const float4* xr = (const float4*)(x + (size_t)row * DFEAT);
        float prod = 1.f;
#pragma unroll
        for (int it = 0; it < DFEAT / (64 * 4); ++it) {   // 8 iters, 1 KiB/instr
            float4 v = xr[it * 64 + lane];
            prod *= (v.x * v.y) * (v.z * v.w);
        }
#pragma unroll
        for (int off = 32; off > 0; off >>= 1)            // wave-wide product
            prod *= __shfl_xor(prod, off);
        if (lane == 0) prodbuf[row] = prod;
        return;
    }

    // ==================== chain block (blockIdx.x < 32) =====================
    const int ri = lane >> 2;             // row 0..15 (this lane's A/F row)
    const int c0 = (lane & 3) << 2;       // col base 0,4,8,12
    const size_t d0 = (size_t)blockIdx.x * CHUNK;

    // ---- per-wave fold of 16 matrices, wave-synchronous (no barriers) ----
    // ALL 16 cores loaded up front into registers: 16 outstanding 1-KiB
    // loads per wave, one latency exposure (vs round-9's serial depth-1).
    // (lane*4 floats == ri*16 + c0, so the coalesced float4 load per lane
    //  lands exactly at this lane's (ri, c0..c0+3) slot.)
    const float* gw = cores + (d0 + 16 * wave) * NR2;
    float4 pre[16];
#pragma unroll
    for (int t = 0; t < 16; ++t)
        pre[t] = *(const float4*)&gw[(size_t)t * NR2 + lane * 4];

    *(float4*)&Aw[wave][0][lane * 4] = pre[0];         // A = core0
    int cur = 0;
#pragma unroll
    for (int t = 1; t < 16; ++t) {        // 15 multiplies -> result in buf 1
        *(float4*)&Bb[wave][t & 1][lane * 4] = pre[t]; // stash core t
        float4 r = rowmul(&Aw[wave][cur][ri * 16], &Bb[wave][t & 1][0], c0);
        *(float4*)&Aw[wave][cur ^ 1][ri * 16 + c0] = r;
        cur ^= 1;
    }
    __syncthreads();                      // all 4 wave-products ready

    // ---- wave 0 combines: F = Aw0 x Aw1 x Aw2 x Aw3 (3 multiplies) ----
    if (wave == 0) {
        *(float4*)&F[0][ri * 16 + c0] =
            *(const float4*)&Aw[0][1][ri * 16 + c0];
        int cc = 0;
        for (int w = 1; w < 4; ++w) {     // 3 multiplies -> result in F[1]
            float4 r = rowmul(&F[cc][ri * 16], &Aw[w][1][0], c0);
            *(float4*)&F[cc ^ 1][ri * 16 + c0] = r;
            cc ^= 1;
        }
    }
    __syncthreads();
    const int i = tid >> 4, j = tid & 15;
    const float v = F[1][tid];            // element (i,j) of chunk product

    if (blockIdx.x != 0) {
        // ---- producer: publish partial, release flag (verbatim) ----
        partials[blockIdx.x * NR2 + tid] = v;
        __syncthreads();                  // block stores complete at L2
        if (tid == 0)
            __hip_atomic_store(&flags[blockIdx.x], MAGIC,
                               __ATOMIC_RELEASE, __HIP_MEMORY_SCOPE_AGENT);
        return;
    }

    // ---- block 0: own partial straight into LDS slot 0 (transposed) ----
    Pt[0 * 256 + j * 16 + i] = v;

    // acquire-spin for producers 1..31 (every thread: cache-inv side effect)
    // SAFE at this scale: 4 waves spinning, proven in rounds 1/2.
    {
        const int f = 1 + (tid % (NCHUNK - 1));
        while (__hip_atomic_load(&flags[f], __ATOMIC_ACQUIRE,
                                 __HIP_MEMORY_SCOPE_AGENT) != MAGIC) { }
    }
    __syncthreads();

    // ---- 4 rounds: stage 8 partials transposed (8 KB) + wave-0 fold ----
    float w = 1.f;                        // fold state lives in wave-0 regs
    int E = 0;
    for (int rr = 0; rr < 4; ++rr) {
#pragma unroll
        for (int q = 0; q < 2; ++q) {                 // 512 float4 / round
            const int idx = q * 256 + tid;
            const int flat = idx * 4;
            const int s = flat >> 8;                  // local slot 0..7
            if (rr > 0 || s > 0) {                    // slot 0 of rr=0 = own
                float4 p4 =
                    ((const float4*)(partials + (size_t)(8 * rr) * NR2))[idx];
                const int e = flat & 255;
                const int k = e >> 4, j0 = e & 15;    // row k, cols j0..j0+3
                Pt[s * 256 + (j0 + 0) * 16 + k] = p4.x;
                Pt[s * 256 + (j0 + 1) * 16 + k] = p4.y;
                Pt[s * 256 + (j0 + 2) * 16 + k] = p4.z;
                Pt[s * 256 + (j0 + 3) * 16 + k] = p4.w;
            }
        }
        __syncthreads();
        if (tid < 64) {                   // wave-0 register fold, 8 per round
            const int jj = tid & 15, q = tid >> 4;    // lane = jj + 16*q
            for (int s = 0; s < 8; ++s) {
                const float4 pr = *(const float4*)&Pt[s * 256 + jj * 16 + 4 * q];
                float sum;
                sum = __shfl(w, 4 * q + 0) * pr.x;    // w[k] lives at lane k
                sum = fmaf(__shfl(w, 4 * q + 1), pr.y, sum);
                sum = fmaf(__shfl(w, 4 * q + 2), pr.z, sum);
                sum = fmaf(__shfl(w, 4 * q + 3), pr.w, sum);
                sum += __shfl_xor(sum, 16);           // sum the 4 q-groups
                sum += __shfl_xor(sum, 32);           // -> nw[jj], replicated
                w = sum;
            }
            // renorm once per round (global gg = 8*rr+7 -> gg&7==7, as before)
            float m = fabsf(w);
#pragma unroll
            for (int off = 1; off <= 8; off <<= 1)
                m = fmaxf(m, __shfl_xor(m, off));
            if (m > 0.f) {
                int e2 = 0;
                (void)frexpf(m, &e2);                 // m = f*2^e, f in [.5,1)
                w = ldexpf(w, -e2);                   // exact rescale
                E += e2;
            }
        }
        __syncthreads();                  // Pt reusable next round
    }

    if (tid < 64) {
        // p[o] = sum_k w[k] * proj[k][o]
        float p = 0.f;
#pragma unroll
        for (int k = 0; k < R; ++k)
            p = fmaf(__shfl(w, k), proj[k * OUTD + tid], p);
        pE[tid] = p;
        if (tid == 0) ((int*)pE)[OUTD] = E;
    }
}

// ---------------------------------------------------------------------------
// Epilogue: out[b][o] = ldexp(pE[o] * prod[b], E) + bias[o]. 2 MB coalesced.
// ---------------------------------------------------------------------------
__global__ __launch_bounds__(256) void mps_scale(const float* __restrict__ prodbuf,
                                                 const float* __restrict__ pE,
                                                 const float* __restrict__ bias,
                                                 float* __restrict__ out,
                                                 int B) {
    const int gtid = blockIdx.x * 256 + threadIdx.x;
    const int row  = gtid >> 6;
    const int lane = threadIdx.x & 63;
    if (row >= B) return;
    const float pv = pE[lane];                        // lane < 64 == OUTD
    const int   E  = ((const int*)pE)[OUTD];
    out[(size_t)row * OUTD + lane] = ldexpf(pv * prodbuf[row], E) + bias[lane];
}

// ---------------------------------------------------------------------------
extern "C" void kernel_launch(void* const* d_in, const int* in_sizes, int n_in,
                              void* d_out, int out_size, void* d_ws, size_t ws_size,
                              hipStream_t stream) {
    const float* inputs = (const float*)d_in[0];   // (B, 2048) fp32
    const float* cores  = (const float*)d_in[1];   // (2048, 16, 16) fp32
    const float* proj   = (const float*)d_in[2];   // (16, 64) fp32
    const float* bias   = (const float*)d_in[3];   // (64,) fp32
    float* out = (float*)d_out;                    // (B, 64) fp32

    const int B = in_sizes[0] / DFEAT;             // 8192

    // ws layout (16B aligned): prodbuf | partials | pE (64f + E) | flags
    float* prodbuf  = (float*)d_ws;                // B floats (32 KiB)
    float* partials = prodbuf + B;                 // 32*256 floats (32 KiB)
    float* pE    = partials + NCHUNK * NR2;        // 64 floats + int E (+pad)
    int*   flags = (int*)(pE + 68);                // 32 ints; harness poison
                                                   // != MAGIC each replay

    const int rowBlocks = (B + 3) / 4;             // 4 rows (waves) per block
    mps_fused<<<NCHUNK + rowBlocks, 256, 0, stream>>>(cores, proj, inputs,
                                                      prodbuf, partials, flags,
                                                      pE, B);
    mps_scale<<<(B * 64 + 255) / 256, 256, 0, stream>>>(prodbuf, pE, bias,
                                                        out, B);
}